// Round 1
// baseline (411.283 us; speedup 1.0000x reference)
//
#include <hip/hip_runtime.h>

// Lorenz RK4: B=16384 trajectories, NT=2000 steps, dt=0.01.
// Output layout: out[b*3*2001 + d*2001 + t], t=0 is x0.
// Strategy:
//  - 1 wave (64 threads) per block, 1 trajectory per lane, state in registers.
//  - IEEE fp32, NO FMA contraction (match XLA's per-op rounding; chaotic-ish
//    system demands matching the reference arithmetic closely).
//  - Stage 64-step tiles in LDS (stride 65 padding -> conflict-free), flush
//    with coalesced 64-consecutive-float row stores.

#define NTSTEPS 2000
#define TT      64     // time-tile
#define BTRAJ   64     // trajectories per block (one wave)
#define TROWS   2001   // output row length (NT+1)

__global__ __launch_bounds__(64) void lorenz_rk4_kernel(
    const float* __restrict__ x0,
    const float* __restrict__ p,
    float* __restrict__ out)
{
#pragma clang fp contract(off)
    __shared__ float lds[3][TT][BTRAJ + 1];   // +1 pad: (lane+r)%32 banking

    const int lane = threadIdx.x;
    const int b0   = blockIdx.x * BTRAJ;
    const int b    = b0 + lane;

    const float p0 = p[0];
    const float p1 = p[1];
    const float p2 = p[2];

    float x = x0[3 * b + 0];
    float y = x0[3 * b + 1];
    float z = x0[3 * b + 2];

    const float dt = 0.01f;
    const float h2 = dt / 2.0f;   // compile-time IEEE fold, == jnp dt/2
    const float h6 = dt / 6.0f;   // compile-time IEEE fold, == jnp dt/6

    // t = 0 output is the initial state
    {
        size_t base = (size_t)b * (3 * TROWS);
        out[base]             = x;
        out[base + TROWS]     = y;
        out[base + 2 * TROWS] = z;
    }

    int t = 0;
    while (t < NTSTEPS) {
        const int tile = (NTSTEPS - t) < TT ? (NTSTEPS - t) : TT;

        for (int tl = 0; tl < tile; ++tl) {
            // k1 = f(X)
            float k1x = p0 * (y - x);
            float k1y = x * (p1 - z) - y;
            float k1z = x * y - p2 * z;
            // X + dt/2 * k1
            float ax = x + h2 * k1x;
            float ay = y + h2 * k1y;
            float az = z + h2 * k1z;
            // k2
            float k2x = p0 * (ay - ax);
            float k2y = ax * (p1 - az) - ay;
            float k2z = ax * ay - p2 * az;
            // X + dt/2 * k2
            float bx = x + h2 * k2x;
            float by = y + h2 * k2y;
            float bz = z + h2 * k2z;
            // k3
            float k3x = p0 * (by - bx);
            float k3y = bx * (p1 - bz) - by;
            float k3z = bx * by - p2 * bz;
            // X + dt * k3
            float cx = x + dt * k3x;
            float cy = y + dt * k3y;
            float cz = z + dt * k3z;
            // k4
            float k4x = p0 * (cy - cx);
            float k4y = cx * (p1 - cz) - cy;
            float k4z = cx * cy - p2 * cz;
            // Xn = X + dt/6 * (((k1 + 2*k2) + 2*k3) + k4)   [left-assoc like Python]
            float sx = k1x + 2.0f * k2x + 2.0f * k3x + k4x;
            float sy = k1y + 2.0f * k2y + 2.0f * k3y + k4y;
            float sz = k1z + 2.0f * k2z + 2.0f * k3z + k4z;

            x = x + h6 * sx;
            y = y + h6 * sy;
            z = z + h6 * sz;

            lds[0][tl][lane] = x;
            lds[1][tl][lane] = y;
            lds[2][tl][lane] = z;
        }

        // Flush tile: lane covers time index (t + lane) of each row.
        // Stores are 64 consecutive floats per row -> fully coalesced.
        // LDS read lds[d][lane][r]: word addr = lane*65 + r -> bank (lane+r)%32,
        // exactly 2 lanes per bank = free.
        for (int r = 0; r < BTRAJ; ++r) {
            if (lane < tile) {
                size_t base = (size_t)(b0 + r) * (3 * TROWS) + 1 + t + lane;
                out[base]             = lds[0][lane][r];
                out[base + TROWS]     = lds[1][lane][r];
                out[base + 2 * TROWS] = lds[2][lane][r];
            }
        }
        // Single wave per block: LDS pipe is in-order per wave, no barrier
        // needed between flush reads and next tile's writes.
        t += tile;
    }
}

extern "C" void kernel_launch(void* const* d_in, const int* in_sizes, int n_in,
                              void* d_out, int out_size, void* d_ws, size_t ws_size,
                              hipStream_t stream)
{
    const float* x0  = (const float*)d_in[0];
    const float* p   = (const float*)d_in[1];
    float*       out = (float*)d_out;

    const int B = in_sizes[0] / 3;          // 16384
    const int nblocks = B / BTRAJ;          // 256

    lorenz_rk4_kernel<<<nblocks, BTRAJ, 0, stream>>>(x0, p, out);
}